// Round 13
// baseline (229.665 us; speedup 1.0000x reference)
//
#include <hip/hip_runtime.h>
#include <hip/hip_fp16.h>

#define BB   8
#define CC   64
#define HH   128
#define WW   128
#define OCC  128
#define HWx  (HH*WW)
#define KTOT 576
#define SST  584    // ushort row stride: 576 + 8 (1168 B, 16B-multiple)

typedef __attribute__((ext_vector_type(8))) short short8t;
typedef __attribute__((ext_vector_type(8))) _Float16 half8t;
typedef __attribute__((ext_vector_type(4))) float f32x4;

static __device__ __forceinline__ ushort f2h(float f) {
    __half h = __float2half_rn(f);
    return __half_as_ushort(h);
}

// ---- K0: conv_w [oc][c*9+tap] fp32 -> wb [oc][tap*64+c] fp16 --------------
__global__ __launch_bounds__(256) void kprep(const float* __restrict__ w,
                                             ushort* __restrict__ wb) {
    int i = blockIdx.x * 256 + threadIdx.x;   // 73728
    int oc = i / KTOT, k = i - oc * KTOT;
    int c = k / 9, tap = k - c * 9;
    wb[oc * KTOT + tap * 64 + c] = f2h(w[i]);
}

// ---- K0c: off_w [ch][c*9+tap] -> wT [(c*9+tap)*18 + ch] fp32 --------------
__global__ __launch_bounds__(256) void kprepw(const float* __restrict__ ow,
                                              float* __restrict__ wT) {
    int i = blockIdx.x * 256 + threadIdx.x;   // 18*576 = 10368
    if (i < 18 * KTOT) {
        int ch = i / KTOT, r = i - ch * KTOT;
        wT[r * 18 + ch] = ow[i];
    }
}

// ---- K0b: x NCHW fp32 -> xT NHWC fp16, direct -----------------------------
__global__ __launch_bounds__(256) void ktrans(const float* __restrict__ x,
                                              ushort* __restrict__ xT) {
    int tid = threadIdx.x;
    int b   = blockIdx.x >> 8;
    int p   = (blockIdx.x & 255) * 64 + (tid & 63);
    int cg  = tid >> 6;                  // 0..3 -> channels cg*16..+15
    const float* xb = x + (size_t)b * CC * HWx + p;
    ushort* ob = xT + ((size_t)b * HWx + p) * 64 + cg * 16;
    short8t v0, v1;
#pragma unroll
    for (int e = 0; e < 8; ++e) v0[e] = (short)f2h(xb[(size_t)(cg * 16 + e) * HWx]);
#pragma unroll
    for (int e = 0; e < 8; ++e) v1[e] = (short)f2h(xb[(size_t)(cg * 16 + 8 + e) * HWx]);
    *(short8t*)ob = v0;
    *(short8t*)(ob + 8) = v1;
}

// ---- K1: offset conv (ch 0..17), fp32 exact, LDS-free, reg-pipelined ------
// grid = BB*HH = 1024, b = bi&7. g = tid>>7 channel half. FMA order == R12.
__global__ __launch_bounds__(256) void koff6(const float* __restrict__ x,
                                             const float* __restrict__ wT,
                                             const float* __restrict__ off_b,
                                             float* __restrict__ offsT) {
    int tid = threadIdx.x;
    int b = blockIdx.x & 7;
    int i = blockIdx.x >> 3;
    int g9 = __builtin_amdgcn_readfirstlane((tid >> 7) * 9);  // wave-uniform
    int j = tid & 127;
    const float* xb = x + (size_t)b * CC * HWx;

    bool rv0 = (i - 1 >= 0), rv2 = (i + 1 < HH);
    bool cv0 = (j - 1 >= 0), cv2 = (j + 1 < WW);

    float acc[9];
#pragma unroll
    for (int u = 0; u < 9; ++u) acc[u] = off_b[g9 + u];

#define KOFF_LOAD(c, xv) { \
    const float* xc = xb + (size_t)(c) * HWx; \
    xv[0] = (rv0 && cv0) ? xc[(i-1)*WW + j-1] : 0.f; \
    xv[1] = (rv0)        ? xc[(i-1)*WW + j  ] : 0.f; \
    xv[2] = (rv0 && cv2) ? xc[(i-1)*WW + j+1] : 0.f; \
    xv[3] = (cv0)        ? xc[(i  )*WW + j-1] : 0.f; \
    xv[4] =                xc[(i  )*WW + j  ]; \
    xv[5] = (cv2)        ? xc[(i  )*WW + j+1] : 0.f; \
    xv[6] = (rv2 && cv0) ? xc[(i+1)*WW + j-1] : 0.f; \
    xv[7] = (rv2)        ? xc[(i+1)*WW + j  ] : 0.f; \
    xv[8] = (rv2 && cv2) ? xc[(i+1)*WW + j+1] : 0.f; }

#define KOFF_FMA(c, xv) { \
    const float* wbase = &wT[((c) * 9) * 18 + g9]; \
    _Pragma("unroll") \
    for (int t = 0; t < 9; ++t) { \
        _Pragma("unroll") \
        for (int u = 0; u < 9; ++u) \
            acc[u] = fmaf(xv[t], wbase[t * 18 + u], acc[u]); \
    } }

    float xva[9], xvb[9];
    KOFF_LOAD(0, xva)
#pragma unroll 2
    for (int c = 0; c < CC; c += 2) {
        KOFF_LOAD(c + 1, xvb)
        KOFF_FMA(c, xva)
        if (c + 2 < CC) KOFF_LOAD(c + 2, xva)
        KOFF_FMA(c + 1, xvb)
    }

    float* ob = offsT + ((size_t)(b * HWx) + i * WW + j) * 18 + g9;
#pragma unroll
    for (int u = 0; u < 9; ++u) ob[u] = acc[u];
}

// ---- per-chain macros for kmain phase 1 (identical math to R12) -----------
#define CHAIN_DECODE(q, SS) \
    const int s##q = (SS); \
    const int pix##q = s##q / 72; \
    const int rr##q = s##q - pix##q * 72; \
    const int tap##q = rr##q >> 3; \
    const int cg##q = rr##q & 7; \
    const int kr##q = tap##q / 3, kc##q = tap##q - kr##q * 3; \
    const int si##q = oi + ((kr##q == 0) ? -1 : 0); \
    const int sj##q = oj0v + pix##q + ((kc##q == 0) ? -1 : 0); \
    const bool v##q = (si##q >= 0) && (sj##q >= 0); \
    const int n##q = ((kr##q == 0) ? 2 : kr##q - 1) * 3 + ((kc##q == 0) ? 2 : kc##q - 1); \
    const int pidx##q = v##q ? (si##q * WW + sj##q) : 0; \
    const float ox##q = offb[pidx##q * 18 + n##q]; \
    const float oy##q = offb[pidx##q * 18 + 9 + n##q];

#define CHAIN_ADDR(q) \
    float px##q = (float)si##q + ox##q; \
    float py##q = (float)sj##q + oy##q; \
    float fx##q = floorf(px##q), fy##q = floorf(py##q); \
    float pxc##q   = fminf(fmaxf(px##q, 0.f), 127.f); \
    float pyc##q   = fminf(fmaxf(py##q, 0.f), 127.f); \
    float qltxf##q = fminf(fmaxf(fx##q, 0.f), 127.f); \
    float qltyf##q = fminf(fmaxf(fy##q, 0.f), 127.f); \
    float qrbxf##q = fminf(fmaxf(fx##q + 1.f, 0.f), 127.f); \
    float qrbyf##q = fminf(fmaxf(fy##q + 1.f, 0.f), 127.f); \
    int qltx##q = (int)qltxf##q, qlty##q = (int)qltyf##q; \
    int qrbx##q = (int)qrbxf##q, qrby##q = (int)qrbyf##q; \
    const int co##q = cg##q * 8; \
    uint4 lt##q = *(const uint4*)(xTb + (size_t)(qltx##q * WW + qlty##q) * 64 + co##q); \
    uint4 rb##q = *(const uint4*)(xTb + (size_t)(qrbx##q * WW + qrby##q) * 64 + co##q); \
    uint4 lb##q = *(const uint4*)(xTb + (size_t)(qltx##q * WW + qrby##q) * 64 + co##q); \
    uint4 rt##q = *(const uint4*)(xTb + (size_t)(qrbx##q * WW + qlty##q) * 64 + co##q); \
    float glt##q = (1.f + (qltxf##q - pxc##q)) * (1.f + (qltyf##q - pyc##q)); \
    float grb##q = (1.f - (qrbxf##q - pxc##q)) * (1.f - (qrbyf##q - pyc##q)); \
    float glb##q = (1.f + (qltxf##q - pxc##q)) * (1.f - (qrbyf##q - pyc##q)); \
    float grt##q = (1.f - (qrbxf##q - pxc##q)) * (1.f + (qltyf##q - pyc##q));

#define LERP1(q, comp) \
    a = __hmul2(hlt, __builtin_bit_cast(__half2, lt##q.comp)); \
    a = __hfma2(hrb, __builtin_bit_cast(__half2, rb##q.comp), a); \
    a = __hfma2(hlb, __builtin_bit_cast(__half2, lb##q.comp), a); \
    a = __hfma2(hrt, __builtin_bit_cast(__half2, rt##q.comp), a);

#define CHAIN_FINISH(q) { \
    __half2 hlt = __float2half2_rn(glt##q); \
    __half2 hrb = __float2half2_rn(grb##q); \
    __half2 hlb = __float2half2_rn(glb##q); \
    __half2 hrt = __float2half2_rn(grt##q); \
    uint4 o; __half2 a; \
    LERP1(q, x) o.x = __builtin_bit_cast(uint, a); \
    LERP1(q, y) o.y = __builtin_bit_cast(uint, a); \
    LERP1(q, z) o.z = __builtin_bit_cast(uint, a); \
    LERP1(q, w) o.w = __builtin_bit_cast(uint, a); \
    if (!v##q) { o.x = 0u; o.y = 0u; o.z = 0u; o.w = 0u; } \
    *(uint4*)(&Sb[pix##q * SST + tap##q * 64 + cg##q * 8]) = o; }

#define MFMA_CHUNK(K0, K1, SP0, SP1) \
    _Pragma("unroll") \
    for (int ks = (K0); ks < (K1); ++ks) { \
        int kk = ks * 32; \
        half8t a0 = *(const half8t*)(wr0 + kk); \
        half8t b0 = *(const half8t*)((SP0) + kk); \
        half8t b1 = *(const half8t*)((SP1) + kk); \
        acc[0] = __builtin_amdgcn_mfma_f32_16x16x32_f16(a0, b0, acc[0], 0, 0, 0); \
        acc[1] = __builtin_amdgcn_mfma_f32_16x16x32_f16(a0, b1, acc[1], 0, 0, 0); \
    }

#define STORE_TILE(OJ) { \
    float* ob = out + ((size_t)b * OCC * HH + oi) * WW + (OJ); \
    _Pragma("unroll") \
    for (int p = 0; p < 2; ++p) { \
        _Pragma("unroll") \
        for (int e = 0; e < 4; ++e) { \
            int oc  = 16 * wv + lg * 4 + e; \
            int col = 16 * p + lr; \
            ob[(size_t)oc * HWx + col] = acc[p][e]; \
        } \
    } }

// ---- K2: fused gather + MFMA, 2-tile software pipeline ---------------------
// Block: 512 thr, 64 pixels (2 tiles x 32) x 128 oc. grid = 2048, b = bi&7.
// LDS 74.75 KB -> 2 blocks/CU. Tile1 gather overlaps tile0 MFMA (no barrier
// between: disjoint LDS buffers).
__global__ __launch_bounds__(512, 4) void kmain13(const ushort* __restrict__ xT,
                                                  const float* __restrict__ offsT,
                                                  const ushort* __restrict__ wb,
                                                  const float* __restrict__ conv_b,
                                                  float* __restrict__ out) {
    __shared__ __align__(16) ushort S[2][32 * SST];   // 2 x 37376 B
    int tid = threadIdx.x;                 // 0..511
    int bi  = blockIdx.x;
    int b   = bi & 7;                      // XCD-affine batch
    int rem = bi >> 3;                     // 0..255
    int oi  = rem >> 1;                    // row
    int ojh = (rem & 1) * 64;              // half-row base

    const ushort* xTb  = xT + (size_t)b * HWx * 64;
    const float*  offb = offsT + (size_t)b * HWx * 18;

    int wv = tid >> 6;                     // wave 0..7: oc tile [16wv,16wv+16)
    int l  = tid & 63;
    int lr = l & 15;
    int lg = l >> 4;
    const ushort* wr0 = wb + (size_t)(16 * wv + lr) * KTOT + lg * 8;

    float bias[4];
#pragma unroll
    for (int e = 0; e < 4; ++e) bias[e] = conv_b[16 * wv + lg * 4 + e];

    // ---- pipeline fill: gather tile 0 -> S[0] ----
    {
        int oj0v = ojh;
        ushort* Sb = &S[0][0];
        CHAIN_DECODE(0, tid)
        CHAIN_DECODE(1, tid + 512)
        CHAIN_DECODE(2, tid + 1024)
        CHAIN_DECODE(3, tid + 1536)
        CHAIN_ADDR(0)
        CHAIN_ADDR(1)
        CHAIN_ADDR(2)
        CHAIN_ADDR(3)
        CHAIN_FINISH(0)
        CHAIN_FINISH(1)
        CHAIN_FINISH(2)
        CHAIN_FINISH(3)
        if (tid < 256) {
            CHAIN_DECODE(4, tid + 2048)
            CHAIN_ADDR(4)
            CHAIN_FINISH(4)
        }
    }
    __syncthreads();

    const ushort* sp0 = &S[0][(lr) * SST + lg * 8];
    const ushort* sp1 = &S[0][(16 + lr) * SST + lg * 8];
    f32x4 acc[2];
#pragma unroll
    for (int e = 0; e < 4; ++e) { acc[0][e] = bias[e]; acc[1][e] = bias[e]; }

    // ---- steady state: gather tile1 (S[1]) interleaved with MFMA tile0 ----
    {
        int oj0v = ojh + 32;
        ushort* Sb = &S[1][0];
        CHAIN_DECODE(0, tid)
        CHAIN_DECODE(1, tid + 512)
        CHAIN_ADDR(0)
        CHAIN_ADDR(1)
        MFMA_CHUNK(0, 6, sp0, sp1)
        CHAIN_FINISH(0)
        CHAIN_FINISH(1)
        CHAIN_DECODE(2, tid + 1024)
        CHAIN_DECODE(3, tid + 1536)
        CHAIN_ADDR(2)
        CHAIN_ADDR(3)
        MFMA_CHUNK(6, 12, sp0, sp1)
        CHAIN_FINISH(2)
        CHAIN_FINISH(3)
        if (tid < 256) {
            CHAIN_DECODE(4, tid + 2048)
            CHAIN_ADDR(4)
            CHAIN_FINISH(4)
        }
        MFMA_CHUNK(12, 18, sp0, sp1)
    }
    STORE_TILE(ojh)
    __syncthreads();

    // ---- drain: MFMA tile 1 ----
    {
        const ushort* tp0 = &S[1][(lr) * SST + lg * 8];
        const ushort* tp1 = &S[1][(16 + lr) * SST + lg * 8];
#pragma unroll
        for (int e = 0; e < 4; ++e) { acc[0][e] = bias[e]; acc[1][e] = bias[e]; }
        MFMA_CHUNK(0, 18, tp0, tp1)
    }
    STORE_TILE(ojh + 32)
}

extern "C" void kernel_launch(void* const* d_in, const int* in_sizes, int n_in,
                              void* d_out, int out_size, void* d_ws, size_t ws_size,
                              hipStream_t stream) {
    const float* x      = (const float*)d_in[0];
    const float* off_w  = (const float*)d_in[1];
    const float* off_b  = (const float*)d_in[2];
    const float* conv_w = (const float*)d_in[3];
    const float* conv_b = (const float*)d_in[4];
    float* out = (float*)d_out;

    ushort* wbf   = (ushort*)d_ws;                              // 147456 B
    float*  offsT = (float*)((char*)d_ws + 147456);             // 9.44 MB
    ushort* xT    = (ushort*)((char*)d_ws + 147456 + 9437184);  // 16.78 MB
    float*  wT    = (float*)((char*)d_ws + 147456 + 9437184 + 16777216); // 41.5 KB

    kprep<<<(OCC * KTOT) / 256, 256, 0, stream>>>(conv_w, wbf);
    kprepw<<<41, 256, 0, stream>>>(off_w, wT);
    ktrans<<<BB * (HWx / 64), 256, 0, stream>>>(x, xT);
    koff6<<<BB * HH, 256, 0, stream>>>(x, wT, off_b, offsT);
    kmain13<<<BB * HH * 2, 512, 0, stream>>>(xT, offsT, wbf, conv_b, out);
}

// Round 14
// 175.132 us; speedup vs baseline: 1.3114x; 1.3114x over previous
//
#include <hip/hip_runtime.h>
#include <hip/hip_fp16.h>

#define BB   8
#define CC   64
#define HH   128
#define WW   128
#define OCC  128
#define HWx  (HH*WW)
#define KTOT 576
#define SST  584    // ushort row stride: 576 + 8 (1168 B, 16B-multiple)

typedef __attribute__((ext_vector_type(8))) short short8t;
typedef __attribute__((ext_vector_type(8))) _Float16 half8t;
typedef __attribute__((ext_vector_type(4))) float f32x4;

static __device__ __forceinline__ ushort f2h(float f) {
    __half h = __float2half_rn(f);
    return __half_as_ushort(h);
}

// ---- K0: conv_w [oc][c*9+tap] fp32 -> wb [oc][tap*64+c] fp16 --------------
__global__ __launch_bounds__(256) void kprep(const float* __restrict__ w,
                                             ushort* __restrict__ wb) {
    int i = blockIdx.x * 256 + threadIdx.x;   // 73728
    int oc = i / KTOT, k = i - oc * KTOT;
    int c = k / 9, tap = k - c * 9;
    wb[oc * KTOT + tap * 64 + c] = f2h(w[i]);
}

// ---- K0c: off_w [ch][c*9+tap] -> wT [(c*9+tap)*18 + ch] fp32 --------------
__global__ __launch_bounds__(256) void kprepw(const float* __restrict__ ow,
                                              float* __restrict__ wT) {
    int i = blockIdx.x * 256 + threadIdx.x;   // 18*576 = 10368
    if (i < 18 * KTOT) {
        int ch = i / KTOT, r = i - ch * KTOT;
        wT[r * 18 + ch] = ow[i];
    }
}

// ---- K0b: x NCHW fp32 -> xT NHWC fp16, direct -----------------------------
__global__ __launch_bounds__(256) void ktrans(const float* __restrict__ x,
                                              ushort* __restrict__ xT) {
    int tid = threadIdx.x;
    int b   = blockIdx.x >> 8;
    int p   = (blockIdx.x & 255) * 64 + (tid & 63);
    int cg  = tid >> 6;                  // 0..3 -> channels cg*16..+15
    const float* xb = x + (size_t)b * CC * HWx + p;
    ushort* ob = xT + ((size_t)b * HWx + p) * 64 + cg * 16;
    short8t v0, v1;
#pragma unroll
    for (int e = 0; e < 8; ++e) v0[e] = (short)f2h(xb[(size_t)(cg * 16 + e) * HWx]);
#pragma unroll
    for (int e = 0; e < 8; ++e) v1[e] = (short)f2h(xb[(size_t)(cg * 16 + 8 + e) * HWx]);
    *(short8t*)ob = v0;
    *(short8t*)(ob + 8) = v1;
}

// ---- K1: offset conv (ch 0..17), fp32 exact, LDS-free (R12 koff5 verbatim) -
__global__ __launch_bounds__(256) void koff5(const float* __restrict__ x,
                                             const float* __restrict__ wT,
                                             const float* __restrict__ off_b,
                                             float* __restrict__ offsT) {
    int tid = threadIdx.x;
    int b = blockIdx.x & 7;
    int i = blockIdx.x >> 3;
    int g9 = __builtin_amdgcn_readfirstlane((tid >> 7) * 9);  // wave-uniform
    int j = tid & 127;
    const float* xb = x + (size_t)b * CC * HWx;

    float acc[9];
#pragma unroll
    for (int u = 0; u < 9; ++u) acc[u] = off_b[g9 + u];

    for (int c = 0; c < CC; ++c) {
        const float* xc = xb + (size_t)c * HWx;
#pragma unroll
        for (int di = 0; di < 3; ++di) {
            int r = i + di - 1;
            bool rv = (r >= 0) && (r < HH);
#pragma unroll
            for (int dj = 0; dj < 3; ++dj) {
                int s = j + dj - 1;
                float xv = (rv && s >= 0 && s < WW) ? xc[r * WW + s] : 0.f;
                const float* wrow = &wT[(c * 9 + di * 3 + dj) * 18 + g9];
#pragma unroll
                for (int u = 0; u < 9; ++u)
                    acc[u] = fmaf(xv, wrow[u], acc[u]);
            }
        }
    }
    float* ob = offsT + ((size_t)(b * HWx) + i * WW + j) * 18 + g9;
#pragma unroll
    for (int u = 0; u < 9; ++u) ob[u] = acc[u];
}

// ---- 32-channel gather chain: 1 offset load -> 16 independent corner loads -
static __device__ __forceinline__ __half2 lerp_w(uint ltw, uint rbw, uint lbw, uint rtw,
                                                 __half2 hlt, __half2 hrb,
                                                 __half2 hlb, __half2 hrt) {
    __half2 a;
    a = __hmul2(hlt, __builtin_bit_cast(__half2, ltw));
    a = __hfma2(hrb, __builtin_bit_cast(__half2, rbw), a);
    a = __hfma2(hlb, __builtin_bit_cast(__half2, lbw), a);
    a = __hfma2(hrt, __builtin_bit_cast(__half2, rtw), a);
    return a;
}
static __device__ __forceinline__ uint4 lerp_u4(uint4 lt, uint4 rb, uint4 lb, uint4 rt,
                                                __half2 hlt, __half2 hrb,
                                                __half2 hlb, __half2 hrt) {
    uint4 o;
    o.x = __builtin_bit_cast(uint, lerp_w(lt.x, rb.x, lb.x, rt.x, hlt, hrb, hlb, hrt));
    o.y = __builtin_bit_cast(uint, lerp_w(lt.y, rb.y, lb.y, rt.y, hlt, hrb, hlb, hrt));
    o.z = __builtin_bit_cast(uint, lerp_w(lt.z, rb.z, lb.z, rt.z, hlt, hrb, hlb, hrt));
    o.w = __builtin_bit_cast(uint, lerp_w(lt.w, rb.w, lb.w, rt.w, hlt, hrb, hlb, hrt));
    return o;
}

static __device__ __forceinline__ void chain32(int s, int oi, int oj0v,
                                               const float* __restrict__ offb,
                                               const ushort* __restrict__ xTb,
                                               ushort* __restrict__ Sb) {
    int pix  = s / 18;           // 0..31
    int rr   = s - pix * 18;
    int tap  = rr >> 1;
    int half = rr & 1;
    int kr = tap / 3, kc = tap - kr * 3;
    int si = oi + ((kr == 0) ? -1 : 0);
    int sj = oj0v + pix + ((kc == 0) ? -1 : 0);
    bool v = (si >= 0) && (sj >= 0);
    int n    = ((kr == 0) ? 2 : kr - 1) * 3 + ((kc == 0) ? 2 : kc - 1);
    int pidx = v ? (si * WW + sj) : 0;
    float ox = offb[pidx * 18 + n];
    float oy = offb[pidx * 18 + 9 + n];

    float px = (float)si + ox;
    float py = (float)sj + oy;
    float fx = floorf(px), fy = floorf(py);
    float pxc   = fminf(fmaxf(px, 0.f), 127.f);
    float pyc   = fminf(fmaxf(py, 0.f), 127.f);
    float qltxf = fminf(fmaxf(fx, 0.f), 127.f);
    float qltyf = fminf(fmaxf(fy, 0.f), 127.f);
    float qrbxf = fminf(fmaxf(fx + 1.f, 0.f), 127.f);
    float qrbyf = fminf(fmaxf(fy + 1.f, 0.f), 127.f);
    int qltx = (int)qltxf, qlty = (int)qltyf;
    int qrbx = (int)qrbxf, qrby = (int)qrbyf;
    int co = half * 32;
    const ushort* plt = xTb + (size_t)(qltx * WW + qlty) * 64 + co;
    const ushort* prb = xTb + (size_t)(qrbx * WW + qrby) * 64 + co;
    const ushort* plb = xTb + (size_t)(qltx * WW + qrby) * 64 + co;
    const ushort* prt = xTb + (size_t)(qrbx * WW + qlty) * 64 + co;
    // 16 independent 16B loads (one lerp tree consumes all -> stay hoisted)
    uint4 lt0 = *(const uint4*)(plt);      uint4 lt1 = *(const uint4*)(plt + 8);
    uint4 lt2 = *(const uint4*)(plt + 16); uint4 lt3 = *(const uint4*)(plt + 24);
    uint4 rb0 = *(const uint4*)(prb);      uint4 rb1 = *(const uint4*)(prb + 8);
    uint4 rb2 = *(const uint4*)(prb + 16); uint4 rb3 = *(const uint4*)(prb + 24);
    uint4 lb0 = *(const uint4*)(plb);      uint4 lb1 = *(const uint4*)(plb + 8);
    uint4 lb2 = *(const uint4*)(plb + 16); uint4 lb3 = *(const uint4*)(plb + 24);
    uint4 rt0 = *(const uint4*)(prt);      uint4 rt1 = *(const uint4*)(prt + 8);
    uint4 rt2 = *(const uint4*)(prt + 16); uint4 rt3 = *(const uint4*)(prt + 24);

    float glt = (1.f + (qltxf - pxc)) * (1.f + (qltyf - pyc));
    float grb = (1.f - (qrbxf - pxc)) * (1.f - (qrbyf - pyc));
    float glb = (1.f + (qltxf - pxc)) * (1.f - (qrbyf - pyc));
    float grt = (1.f - (qrbxf - pxc)) * (1.f + (qltyf - pyc));
    __half2 hlt = __float2half2_rn(glt);
    __half2 hrb = __float2half2_rn(grb);
    __half2 hlb = __float2half2_rn(glb);
    __half2 hrt = __float2half2_rn(grt);

    uint4 o0 = lerp_u4(lt0, rb0, lb0, rt0, hlt, hrb, hlb, hrt);
    uint4 o1 = lerp_u4(lt1, rb1, lb1, rt1, hlt, hrb, hlb, hrt);
    uint4 o2 = lerp_u4(lt2, rb2, lb2, rt2, hlt, hrb, hlb, hrt);
    uint4 o3 = lerp_u4(lt3, rb3, lb3, rt3, hlt, hrb, hlb, hrt);
    if (!v) {
        uint4 z = {0, 0, 0, 0};
        o0 = z; o1 = z; o2 = z; o3 = z;
    }
    ushort* Sd = &Sb[pix * SST + tap * 64 + co];
    *(uint4*)(Sd)      = o0;
    *(uint4*)(Sd + 8)  = o1;
    *(uint4*)(Sd + 16) = o2;
    *(uint4*)(Sd + 24) = o3;
}

#define MFMA_CHUNK(K0, K1, SP0, SP1) \
    _Pragma("unroll") \
    for (int ks = (K0); ks < (K1); ++ks) { \
        int kk = ks * 32; \
        half8t a0 = *(const half8t*)(wr0 + kk); \
        half8t b0 = *(const half8t*)((SP0) + kk); \
        half8t b1 = *(const half8t*)((SP1) + kk); \
        acc[0] = __builtin_amdgcn_mfma_f32_16x16x32_f16(a0, b0, acc[0], 0, 0, 0); \
        acc[1] = __builtin_amdgcn_mfma_f32_16x16x32_f16(a0, b1, acc[1], 0, 0, 0); \
    }

#define STORE_TILE(OJ) { \
    float* ob = out + ((size_t)b * OCC * HH + oi) * WW + (OJ); \
    _Pragma("unroll") \
    for (int p = 0; p < 2; ++p) { \
        _Pragma("unroll") \
        for (int e = 0; e < 4; ++e) { \
            int oc  = 16 * wv + lg * 4 + e; \
            int col = 16 * p + lr; \
            ob[(size_t)oc * HWx + col] = acc[p][e]; \
        } \
    } }

// ---- K2: fused gather + MFMA, 2-tile pipeline, 32-ch chains ----------------
// Block: 512 thr, 64 pixels (2 tiles x 32) x 128 oc. grid = 2048, b = bi&7.
// 576 chains/tile over 512 thr = ~1.1 chains/thread (chain = 16-wide MLP).
__global__ __launch_bounds__(512, 4) void kmain14(const ushort* __restrict__ xT,
                                                  const float* __restrict__ offsT,
                                                  const ushort* __restrict__ wb,
                                                  const float* __restrict__ conv_b,
                                                  float* __restrict__ out) {
    __shared__ __align__(16) ushort S[2][32 * SST];   // 2 x 37376 B
    int tid = threadIdx.x;                 // 0..511
    int bi  = blockIdx.x;
    int b   = bi & 7;                      // XCD-affine batch
    int rem = bi >> 3;                     // 0..255
    int oi  = rem >> 1;                    // row
    int ojh = (rem & 1) * 64;              // half-row base

    const ushort* xTb  = xT + (size_t)b * HWx * 64;
    const float*  offb = offsT + (size_t)b * HWx * 18;

    int wv = tid >> 6;                     // wave 0..7: oc tile [16wv,16wv+16)
    int l  = tid & 63;
    int lr = l & 15;
    int lg = l >> 4;
    const ushort* wr0 = wb + (size_t)(16 * wv + lr) * KTOT + lg * 8;

    float bias[4];
#pragma unroll
    for (int e = 0; e < 4; ++e) bias[e] = conv_b[16 * wv + lg * 4 + e];

    // ---- pipeline fill: gather tile 0 -> S[0] ----
    chain32(tid, oi, ojh, offb, xTb, &S[0][0]);
    if (tid < 64) chain32(tid + 512, oi, ojh, offb, xTb, &S[0][0]);
    __syncthreads();

    const ushort* sp0 = &S[0][(lr) * SST + lg * 8];
    const ushort* sp1 = &S[0][(16 + lr) * SST + lg * 8];
    f32x4 acc[2];
#pragma unroll
    for (int e = 0; e < 4; ++e) { acc[0][e] = bias[e]; acc[1][e] = bias[e]; }

    // ---- steady state: gather tile1 (S[1]) interleaved with MFMA tile0 ----
    chain32(tid, oi, ojh + 32, offb, xTb, &S[1][0]);
    MFMA_CHUNK(0, 9, sp0, sp1)
    if (tid < 64) chain32(tid + 512, oi, ojh + 32, offb, xTb, &S[1][0]);
    MFMA_CHUNK(9, 18, sp0, sp1)
    STORE_TILE(ojh)
    __syncthreads();

    // ---- drain: MFMA tile 1 ----
    {
        const ushort* tp0 = &S[1][(lr) * SST + lg * 8];
        const ushort* tp1 = &S[1][(16 + lr) * SST + lg * 8];
#pragma unroll
        for (int e = 0; e < 4; ++e) { acc[0][e] = bias[e]; acc[1][e] = bias[e]; }
        MFMA_CHUNK(0, 18, tp0, tp1)
    }
    STORE_TILE(ojh + 32)
}

extern "C" void kernel_launch(void* const* d_in, const int* in_sizes, int n_in,
                              void* d_out, int out_size, void* d_ws, size_t ws_size,
                              hipStream_t stream) {
    const float* x      = (const float*)d_in[0];
    const float* off_w  = (const float*)d_in[1];
    const float* off_b  = (const float*)d_in[2];
    const float* conv_w = (const float*)d_in[3];
    const float* conv_b = (const float*)d_in[4];
    float* out = (float*)d_out;

    ushort* wbf   = (ushort*)d_ws;                              // 147456 B
    float*  offsT = (float*)((char*)d_ws + 147456);             // 9.44 MB
    ushort* xT    = (ushort*)((char*)d_ws + 147456 + 9437184);  // 16.78 MB
    float*  wT    = (float*)((char*)d_ws + 147456 + 9437184 + 16777216); // 41.5 KB

    kprep<<<(OCC * KTOT) / 256, 256, 0, stream>>>(conv_w, wbf);
    kprepw<<<41, 256, 0, stream>>>(off_w, wT);
    ktrans<<<BB * (HWx / 64), 256, 0, stream>>>(x, xT);
    koff5<<<BB * HH, 256, 0, stream>>>(x, wT, off_b, offsT);
    kmain14<<<BB * HH * 2, 512, 0, stream>>>(xT, offsT, wbf, conv_b, out);
}

// Round 15
// 174.530 us; speedup vs baseline: 1.3159x; 1.0035x over previous
//
#include <hip/hip_runtime.h>
#include <hip/hip_fp16.h>

#define BB   8
#define CC   64
#define HH   128
#define WW   128
#define OCC  128
#define HWx  (HH*WW)
#define KTOT 576
#define SST  584    // ushort row stride: 576 + 8 (1168 B, 16B-multiple)

typedef __attribute__((ext_vector_type(8))) short short8t;
typedef __attribute__((ext_vector_type(8))) _Float16 half8t;
typedef __attribute__((ext_vector_type(4))) float f32x4;

static __device__ __forceinline__ ushort f2h(float f) {
    __half h = __float2half_rn(f);
    return __half_as_ushort(h);
}

// ---- K0: conv_w [oc][c*9+tap] fp32 -> wb [oc][tap*64+c] fp16 --------------
__global__ __launch_bounds__(256) void kprep(const float* __restrict__ w,
                                             ushort* __restrict__ wb) {
    int i = blockIdx.x * 256 + threadIdx.x;   // 73728
    int oc = i / KTOT, k = i - oc * KTOT;
    int c = k / 9, tap = k - c * 9;
    wb[oc * KTOT + tap * 64 + c] = f2h(w[i]);
}

// ---- K0c: off_w [ch][c*9+tap] -> wT [(c*9+tap)*18 + ch] fp32 --------------
__global__ __launch_bounds__(256) void kprepw(const float* __restrict__ ow,
                                              float* __restrict__ wT) {
    int i = blockIdx.x * 256 + threadIdx.x;   // 18*576 = 10368
    if (i < 18 * KTOT) {
        int ch = i / KTOT, r = i - ch * KTOT;
        wT[r * 18 + ch] = ow[i];
    }
}

// ---- K0b: x NCHW fp32 -> xT NHWC fp16, direct -----------------------------
__global__ __launch_bounds__(256) void ktrans(const float* __restrict__ x,
                                              ushort* __restrict__ xT) {
    int tid = threadIdx.x;
    int b   = blockIdx.x >> 8;
    int p   = (blockIdx.x & 255) * 64 + (tid & 63);
    int cg  = tid >> 6;                  // 0..3 -> channels cg*16..+15
    const float* xb = x + (size_t)b * CC * HWx + p;
    ushort* ob = xT + ((size_t)b * HWx + p) * 64 + cg * 16;
    short8t v0, v1;
#pragma unroll
    for (int e = 0; e < 8; ++e) v0[e] = (short)f2h(xb[(size_t)(cg * 16 + e) * HWx]);
#pragma unroll
    for (int e = 0; e < 8; ++e) v1[e] = (short)f2h(xb[(size_t)(cg * 16 + 8 + e) * HWx]);
    *(short8t*)ob = v0;
    *(short8t*)(ob + 8) = v1;
}

// ---- K1: offset conv (ch 0..17), fp32 exact, LDS-free ---------------------
__global__ __launch_bounds__(256) void koff5(const float* __restrict__ x,
                                             const float* __restrict__ wT,
                                             const float* __restrict__ off_b,
                                             float* __restrict__ offsT) {
    int tid = threadIdx.x;
    int b = blockIdx.x & 7;
    int i = blockIdx.x >> 3;
    int g9 = __builtin_amdgcn_readfirstlane((tid >> 7) * 9);  // wave-uniform
    int j = tid & 127;
    const float* xb = x + (size_t)b * CC * HWx;

    float acc[9];
#pragma unroll
    for (int u = 0; u < 9; ++u) acc[u] = off_b[g9 + u];

    for (int c = 0; c < CC; ++c) {
        const float* xc = xb + (size_t)c * HWx;
#pragma unroll
        for (int di = 0; di < 3; ++di) {
            int r = i + di - 1;
            bool rv = (r >= 0) && (r < HH);
#pragma unroll
            for (int dj = 0; dj < 3; ++dj) {
                int s = j + dj - 1;
                float xv = (rv && s >= 0 && s < WW) ? xc[r * WW + s] : 0.f;
                const float* wrow = &wT[(c * 9 + di * 3 + dj) * 18 + g9];
#pragma unroll
                for (int u = 0; u < 9; ++u)
                    acc[u] = fmaf(xv, wrow[u], acc[u]);
            }
        }
    }
    float* ob = offsT + ((size_t)(b * HWx) + i * WW + j) * 18 + g9;
#pragma unroll
    for (int u = 0; u < 9; ++u) ob[u] = acc[u];
}

// ---- 32-channel gather chain: 1 offset load -> 16 independent corner loads -
static __device__ __forceinline__ __half2 lerp_w(uint ltw, uint rbw, uint lbw, uint rtw,
                                                 __half2 hlt, __half2 hrb,
                                                 __half2 hlb, __half2 hrt) {
    __half2 a;
    a = __hmul2(hlt, __builtin_bit_cast(__half2, ltw));
    a = __hfma2(hrb, __builtin_bit_cast(__half2, rbw), a);
    a = __hfma2(hlb, __builtin_bit_cast(__half2, lbw), a);
    a = __hfma2(hrt, __builtin_bit_cast(__half2, rtw), a);
    return a;
}
static __device__ __forceinline__ uint4 lerp_u4(uint4 lt, uint4 rb, uint4 lb, uint4 rt,
                                                __half2 hlt, __half2 hrb,
                                                __half2 hlb, __half2 hrt) {
    uint4 o;
    o.x = __builtin_bit_cast(uint, lerp_w(lt.x, rb.x, lb.x, rt.x, hlt, hrb, hlb, hrt));
    o.y = __builtin_bit_cast(uint, lerp_w(lt.y, rb.y, lb.y, rt.y, hlt, hrb, hlb, hrt));
    o.z = __builtin_bit_cast(uint, lerp_w(lt.z, rb.z, lb.z, rt.z, hlt, hrb, hlb, hrt));
    o.w = __builtin_bit_cast(uint, lerp_w(lt.w, rb.w, lb.w, rt.w, hlt, hrb, hlb, hrt));
    return o;
}

static __device__ __forceinline__ void chain32(int s, int oi, int oj0v,
                                               const float* __restrict__ offb,
                                               const ushort* __restrict__ xTb,
                                               ushort* __restrict__ Sb) {
    int pix  = s / 18;           // 0..31
    int rr   = s - pix * 18;
    int tap  = rr >> 1;
    int half = rr & 1;
    int kr = tap / 3, kc = tap - kr * 3;
    int si = oi + ((kr == 0) ? -1 : 0);
    int sj = oj0v + pix + ((kc == 0) ? -1 : 0);
    bool v = (si >= 0) && (sj >= 0);
    int n    = ((kr == 0) ? 2 : kr - 1) * 3 + ((kc == 0) ? 2 : kc - 1);
    int pidx = v ? (si * WW + sj) : 0;
    float ox = offb[pidx * 18 + n];
    float oy = offb[pidx * 18 + 9 + n];

    float px = (float)si + ox;
    float py = (float)sj + oy;
    float fx = floorf(px), fy = floorf(py);
    float pxc   = fminf(fmaxf(px, 0.f), 127.f);
    float pyc   = fminf(fmaxf(py, 0.f), 127.f);
    float qltxf = fminf(fmaxf(fx, 0.f), 127.f);
    float qltyf = fminf(fmaxf(fy, 0.f), 127.f);
    float qrbxf = fminf(fmaxf(fx + 1.f, 0.f), 127.f);
    float qrbyf = fminf(fmaxf(fy + 1.f, 0.f), 127.f);
    int qltx = (int)qltxf, qlty = (int)qltyf;
    int qrbx = (int)qrbxf, qrby = (int)qrbyf;
    int co = half * 32;
    const ushort* plt = xTb + (size_t)(qltx * WW + qlty) * 64 + co;
    const ushort* prb = xTb + (size_t)(qrbx * WW + qrby) * 64 + co;
    const ushort* plb = xTb + (size_t)(qltx * WW + qrby) * 64 + co;
    const ushort* prt = xTb + (size_t)(qrbx * WW + qlty) * 64 + co;
    // 16 independent 16B loads (one lerp tree consumes all)
    uint4 lt0 = *(const uint4*)(plt);      uint4 lt1 = *(const uint4*)(plt + 8);
    uint4 lt2 = *(const uint4*)(plt + 16); uint4 lt3 = *(const uint4*)(plt + 24);
    uint4 rb0 = *(const uint4*)(prb);      uint4 rb1 = *(const uint4*)(prb + 8);
    uint4 rb2 = *(const uint4*)(prb + 16); uint4 rb3 = *(const uint4*)(prb + 24);
    uint4 lb0 = *(const uint4*)(plb);      uint4 lb1 = *(const uint4*)(plb + 8);
    uint4 lb2 = *(const uint4*)(plb + 16); uint4 lb3 = *(const uint4*)(plb + 24);
    uint4 rt0 = *(const uint4*)(prt);      uint4 rt1 = *(const uint4*)(prt + 8);
    uint4 rt2 = *(const uint4*)(prt + 16); uint4 rt3 = *(const uint4*)(prt + 24);

    float glt = (1.f + (qltxf - pxc)) * (1.f + (qltyf - pyc));
    float grb = (1.f - (qrbxf - pxc)) * (1.f - (qrbyf - pyc));
    float glb = (1.f + (qltxf - pxc)) * (1.f - (qrbyf - pyc));
    float grt = (1.f - (qrbxf - pxc)) * (1.f + (qltyf - pyc));
    __half2 hlt = __float2half2_rn(glt);
    __half2 hrb = __float2half2_rn(grb);
    __half2 hlb = __float2half2_rn(glb);
    __half2 hrt = __float2half2_rn(grt);

    uint4 o0 = lerp_u4(lt0, rb0, lb0, rt0, hlt, hrb, hlb, hrt);
    uint4 o1 = lerp_u4(lt1, rb1, lb1, rt1, hlt, hrb, hlb, hrt);
    uint4 o2 = lerp_u4(lt2, rb2, lb2, rt2, hlt, hrb, hlb, hrt);
    uint4 o3 = lerp_u4(lt3, rb3, lb3, rt3, hlt, hrb, hlb, hrt);
    if (!v) {
        uint4 z = {0, 0, 0, 0};
        o0 = z; o1 = z; o2 = z; o3 = z;
    }
    ushort* Sd = &Sb[pix * SST + tap * 64 + co];
    *(uint4*)(Sd)      = o0;
    *(uint4*)(Sd + 8)  = o1;
    *(uint4*)(Sd + 16) = o2;
    *(uint4*)(Sd + 24) = o3;
}

// ---- K2: fused gather + MFMA, single tile, 32-ch chains, max occupancy -----
// Block: 512 thr, 32 pixels x 128 oc. grid = 4096, b = bi&7.
// LDS 37376 B -> 4 blocks/CU x 512 thr = 2048 thr/CU (100% cap).
// 576 chains over 512 thr = 1.125/thread.
__global__ __launch_bounds__(512, 4) void kmain15(const ushort* __restrict__ xT,
                                                  const float* __restrict__ offsT,
                                                  const ushort* __restrict__ wb,
                                                  const float* __restrict__ conv_b,
                                                  float* __restrict__ out) {
    __shared__ __align__(16) ushort S[32 * SST];   // 37376 B
    int tid = threadIdx.x;                 // 0..511
    int bi  = blockIdx.x;
    int b   = bi & 7;                      // XCD-affine batch
    int rem = bi >> 3;                     // 0..511
    int oi  = rem >> 2;
    int oj0 = (rem & 3) * 32;

    const ushort* xTb  = xT + (size_t)b * HWx * 64;
    const float*  offb = offsT + (size_t)b * HWx * 18;

    int wv = tid >> 6;                     // wave 0..7: oc tile [16wv,16wv+16)
    int l  = tid & 63;
    int lr = l & 15;
    int lg = l >> 4;
    const ushort* wr0 = wb + (size_t)(16 * wv + lr) * KTOT + lg * 8;

    // ---- phase 1: 576 chains, 1.125/thread ----
    chain32(tid, oi, oj0, offb, xTb, &S[0]);
    if (tid < 64) chain32(tid + 512, oi, oj0, offb, xTb, &S[0]);
    __syncthreads();

    // ---- phase 2: 128oc x 32pix x 576K GEMM (16x16x32 fp16 MFMA) ----
    f32x4 acc[2];
#pragma unroll
    for (int e = 0; e < 4; ++e) {
        float bv = conv_b[16 * wv + lg * 4 + e];
        acc[0][e] = bv;
        acc[1][e] = bv;
    }
    const ushort* s0 = &S[(lr) * SST + lg * 8];
    const ushort* s1 = &S[(16 + lr) * SST + lg * 8];

#pragma unroll
    for (int ks = 0; ks < 18; ++ks) {
        int kk = ks * 32;
        half8t a0 = *(const half8t*)(wr0 + kk);
        half8t b0 = *(const half8t*)(s0 + kk);
        half8t b1 = *(const half8t*)(s1 + kk);
        acc[0] = __builtin_amdgcn_mfma_f32_16x16x32_f16(a0, b0, acc[0], 0, 0, 0);
        acc[1] = __builtin_amdgcn_mfma_f32_16x16x32_f16(a0, b1, acc[1], 0, 0, 0);
    }

    float* ob = out + ((size_t)b * OCC * HH + oi) * WW + oj0;
#pragma unroll
    for (int p = 0; p < 2; ++p) {
#pragma unroll
        for (int e = 0; e < 4; ++e) {
            int oc  = 16 * wv + lg * 4 + e;
            int col = 16 * p + lr;
            ob[(size_t)oc * HWx + col] = acc[p][e];
        }
    }
}

extern "C" void kernel_launch(void* const* d_in, const int* in_sizes, int n_in,
                              void* d_out, int out_size, void* d_ws, size_t ws_size,
                              hipStream_t stream) {
    const float* x      = (const float*)d_in[0];
    const float* off_w  = (const float*)d_in[1];
    const float* off_b  = (const float*)d_in[2];
    const float* conv_w = (const float*)d_in[3];
    const float* conv_b = (const float*)d_in[4];
    float* out = (float*)d_out;

    ushort* wbf   = (ushort*)d_ws;                              // 147456 B
    float*  offsT = (float*)((char*)d_ws + 147456);             // 9.44 MB
    ushort* xT    = (ushort*)((char*)d_ws + 147456 + 9437184);  // 16.78 MB
    float*  wT    = (float*)((char*)d_ws + 147456 + 9437184 + 16777216); // 41.5 KB

    kprep<<<(OCC * KTOT) / 256, 256, 0, stream>>>(conv_w, wbf);
    kprepw<<<41, 256, 0, stream>>>(off_w, wT);
    ktrans<<<BB * (HWx / 64), 256, 0, stream>>>(x, xT);
    koff5<<<BB * HH, 256, 0, stream>>>(x, wT, off_b, offsT);
    kmain15<<<BB * HH * 4, 512, 0, stream>>>(xT, offsT, wbf, conv_b, out);
}